// Round 13
// baseline (13272.966 us; speedup 1.0000x reference)
//
#include <hip/hip_runtime.h>

typedef unsigned short u16;
typedef __attribute__((ext_vector_type(8))) short bf16x8;
typedef __attribute__((ext_vector_type(4))) float f32x4;

#define MFMA(a,b,c) __builtin_amdgcn_mfma_f32_16x16x32_bf16(a,b,c,0,0,0)

#define B_   128
#define T_   200
#define F_   171
#define FX_  256          // padded frame (8 K-chunks of 32; zero-padded weights)
#define H_   1024
#define G_   4096
#define TF_  (T_*F_)
#define BH_  (B_*H_)
#define NB_  256
#define NT_  512

__device__ __forceinline__ u16 f2bf(float v){
  union { float f; unsigned u; } c; c.f = v;
  unsigned r = (c.u + 0x7fffu + ((c.u >> 16) & 1u)) >> 16;   // RNE
  return (u16)r;
}
__device__ __forceinline__ float bf2f(u16 h){
  union { unsigned u; float f; } c; c.u = ((unsigned)h) << 16; return c.f;
}
__device__ __forceinline__ bf16x8 ld8(const u16* p){
  return *reinterpret_cast<const bf16x8*>(p);
}
// agent-scope write-through stores: visible at MALL, no release fence, no dirty L2 lines
__device__ __forceinline__ void st2a(u16* p, u16 v){
  __hip_atomic_store(p, v, __ATOMIC_RELAXED, __HIP_MEMORY_SCOPE_AGENT);
}
__device__ __forceinline__ void st4a(float* p, float v){
  __hip_atomic_store(p, v, __ATOMIC_RELAXED, __HIP_MEMORY_SCOPE_AGENT);
}
__device__ __forceinline__ float sigm(float v){ return 1.f / (1.f + __expf(-v)); }

// h/if fragment-major layout: tile(bt, kcg) of 16 batch x 32 K stored as 1KB block;
// element (row, khi*8+e) at tile_base + khi*128 + row*8 + e. A wave's A-frag load for
// (bt,kcg) is 64 lanes x 16B = 1KB CONTIGUOUS. h: TPR=32 tiles/row-of-K; if: TPR=8.

// ---------- GLOBAL barrier (flattened): leaf-per-XCD arrive; leaders poll SUM of all
// leaves (saves the root-add RT); ONE L2-inv per XCD by leader; flag via agent-release ----
__device__ __forceinline__ void gbar(unsigned* bar, unsigned ep, int tid,
                                     bool leader, unsigned xcd){
  __syncthreads();                                   // drains vmcnt: st2a/st4a at MALL
  if (tid == 0){
    unsigned* leaf = bar + xcd*16;
    unsigned* flag = bar + 272 + xcd*16;
    __hip_atomic_fetch_add(leaf, 1u, __ATOMIC_RELAXED, __HIP_MEMORY_SCOPE_AGENT);
    if (leader){
      for (;;){
        unsigned s = 0;
#pragma unroll
        for (int i = 0; i < 16; ++i)
          s += __hip_atomic_load(bar + i*16, __ATOMIC_RELAXED, __HIP_MEMORY_SCOPE_AGENT);
        if (s >= ep * (unsigned)NB_) break;
        __builtin_amdgcn_s_sleep(1);
      }
      __builtin_amdgcn_fence(__ATOMIC_ACQUIRE, "agent");   // single buffer_inv, this XCD
      __hip_atomic_store(flag, ep, __ATOMIC_RELEASE, __HIP_MEMORY_SCOPE_AGENT);
    } else {
      while (__hip_atomic_load(flag, __ATOMIC_RELAXED, __HIP_MEMORY_SCOPE_AGENT) < ep)
        __builtin_amdgcn_s_sleep(1);
    }
  }
  asm volatile("" ::: "memory");
  __syncthreads();
}

// ---------- LOCAL (per-XCD) barrier: leaf-only, NO invalidate. Orders Phase-D's plain
// if-stores (dirty local L2) before Phase-A's plain loads on the same XCD. ----
__device__ __forceinline__ void lbar(unsigned* bar, unsigned ep2, int tid,
                                     unsigned xcd, unsigned n_my){
  __syncthreads();
  if (tid == 0){
    unsigned* c = bar + 768 + xcd*16;
    __hip_atomic_fetch_add(c, 1u, __ATOMIC_RELAXED, __HIP_MEMORY_SCOPE_AGENT);
    while (__hip_atomic_load(c, __ATOMIC_RELAXED, __HIP_MEMORY_SCOPE_AGENT) < ep2 * n_my)
      __builtin_amdgcn_s_sleep(1);
  }
  asm volatile("" ::: "memory");
  __syncthreads();
}

// ---------- GEMM on resident weights, fragment-major A (single bf16 stream) ----------
template<int KC, int TPR>
__device__ __forceinline__ void gemm_red_f(
    const bf16x8* wreg, const u16* __restrict__ hb,
    int kcg0, int lane, int w, int r16, int ke, float (*red)[128][20])
{
  f32x4 acc[8];
#pragma unroll
  for (int bt = 0; bt < 8; ++bt) acc[bt] = (f32x4){0,0,0,0};
#pragma unroll
  for (int kc = 0; kc < KC; ++kc){
#pragma unroll
    for (int bt = 0; bt < 8; ++bt){
      const int off = (bt*TPR + kcg0 + kc)*512 + lane*8;
      acc[bt] = MFMA(ld8(hb + off), wreg[kc], acc[bt]);
    }
  }
#pragma unroll
  for (int bt = 0; bt < 8; ++bt)
#pragma unroll
    for (int e = 0; e < 4; ++e)
      red[w][bt*16 + ke*4 + e][r16] = acc[bt][e];
}

// ---------- cell update: thread owns (batch bl, unit u2); block owns cols bid*16.. ----------
__device__ __forceinline__ void cell_update(
    const float* bias4, float& c, bool addgp,
    u16* __restrict__ ohh,
    int bid, int bl, int u2, float (*red)[128][20], float (*gp)[16])
{
  float g[4];
#pragma unroll
  for (int q = 0; q < 4; ++q){
    float s = bias4[q];
#pragma unroll
    for (int ww = 0; ww < 8; ++ww) s += red[ww][bl][q*4 + u2];
    if (addgp) s += gp[bl][q*4 + u2];
    g[q] = s;
  }
  const float cn = sigm(g[1])*c + sigm(g[0])*tanhf(g[2]);
  const float hn = sigm(g[3])*tanhf(cn);
  c = cn;
  const int col = bid*4 + u2;                        // frag-major store position
  const int idx = ((bl >> 4)*32 + (col >> 5))*512 + ((col >> 3) & 3)*128
                + (bl & 15)*8 + (col & 7);
  st2a(ohh + idx, f2bf(hn));
}

// ---------- main persistent kernel: 256 blocks x 512 thr; block = 16 gate-cols, ALL layers ----------
__global__ __attribute__((amdgpu_flat_work_group_size(NT_, NT_)))
           __attribute__((amdgpu_waves_per_eu(2, 2)))
void k_main(
    const float* __restrict__ x, float* __restrict__ out,
    const u16* __restrict__ W1X, const u16* __restrict__ W1H,
    const u16* __restrict__ W2,  const u16* __restrict__ W3,
    const u16* __restrict__ WD,
    const float* __restrict__ bperm, const float* __restrict__ bdec,
    u16* __restrict__ h_hi, u16* __restrict__ if_base,
    unsigned* __restrict__ bar)
{
  const int tid = threadIdx.x, bid = blockIdx.x;
  const int w = tid >> 6, lane = tid & 63, r16 = lane & 15, ke = lane >> 4;
  const int bl = tid >> 2, u2 = tid & 3;             // cell mapping: 128 b x 4 units
  __shared__ float red[8][128][20];                  // 80 KB K-reduce (padded rows)
  __shared__ float gp[128][16];                      // 8 KB L1 h-part stash
  __shared__ unsigned s_info[3];

  // ---- one-time census: per-XCD rank, block count, active-XCD count (proven R9) ----
  unsigned xcc; asm volatile("s_getreg_b32 %0, hwreg(HW_REG_XCC_ID)" : "=s"(xcc));
  xcc &= 15;
  if (tid == 0){
    unsigned* chk   = bar + 528;
    unsigned* iroot = bar + 560;
    const unsigned rank = __hip_atomic_fetch_add(&chk[xcc], 1u, __ATOMIC_RELAXED, __HIP_MEMORY_SCOPE_AGENT);
    __builtin_amdgcn_fence(__ATOMIC_RELEASE, "agent");
    __hip_atomic_fetch_add(iroot, 1u, __ATOMIC_RELAXED, __HIP_MEMORY_SCOPE_AGENT);
    while (__hip_atomic_load(iroot, __ATOMIC_RELAXED, __HIP_MEMORY_SCOPE_AGENT) < (unsigned)NB_)
      __builtin_amdgcn_s_sleep(1);
    __builtin_amdgcn_fence(__ATOMIC_ACQUIRE, "agent");
    s_info[0] = rank;
    s_info[1] = __hip_atomic_load(&chk[xcc], __ATOMIC_RELAXED, __HIP_MEMORY_SCOPE_AGENT);
    s_info[2] = 0;
  }
  __syncthreads();
  const unsigned rank = s_info[0];
  const bool leader = (rank == 0u);
  const unsigned n_my = s_info[1];
  u16* if_own = if_base + (size_t)xcc * (B_ * FX_);  // per-XCD private if buffer

  // ---- resident weights: block's 16 gate-cols for all three layers ----
  const size_t wrow = (size_t)(bid*16 + r16);
  bf16x8 w2r[8], w3r[8], w1h[4], w1x, wdr[4];
#pragma unroll
  for (int kc = 0; kc < 8; ++kc) w2r[kc] = ld8(W2 + wrow*2048 + w*256 + kc*32 + ke*8);
#pragma unroll
  for (int kc = 0; kc < 8; ++kc) w3r[kc] = ld8(W3 + wrow*2048 + w*256 + kc*32 + ke*8);
#pragma unroll
  for (int kc = 0; kc < 4; ++kc) w1h[kc] = ld8(W1H + wrow*1024 + w*128 + kc*32 + ke*8);
  w1x = ld8(W1X + wrow*FX_ + w*32 + ke*8);
  // decoder (ranks 0..10 of each XCD): col-tile = rank, all 128 batches; WD resident
  if (rank < 11u){
#pragma unroll
    for (int kc = 0; kc < 4; ++kc)
      wdr[kc] = ld8(WD + (size_t)(rank*16 + r16)*1024 + w*128 + kc*32 + ke*8);
  } else {
#pragma unroll
    for (int kc = 0; kc < 4; ++kc) wdr[kc] = (bf16x8){0,0,0,0,0,0,0,0};
  }

  float bias[3][4], cs[3] = {0.f, 0.f, 0.f};
#pragma unroll
  for (int l = 0; l < 3; ++l)
#pragma unroll
    for (int q = 0; q < 4; ++q) bias[l][q] = bperm[l*G_ + bid*16 + q*4 + u2];

  // zero the L1 h-part stash (t=0: h0_prev = 0)
  for (int i = tid; i < 128*16; i += NT_) gp[i >> 4][i & 15] = 0.f;
  __syncthreads();

  unsigned ep = 0, ep2 = 0;
  for (int t = 0; t < T_; ++t){
    const int cur = t & 1, prv = cur ^ 1;
    u16* h0c = h_hi + (0*2+cur)*BH_;
    u16* h1c = h_hi + (1*2+cur)*BH_;
    u16* h2c = h_hi + (2*2+cur)*BH_;
    const u16* h1p = h_hi + (1*2+prv)*BH_;
    const u16* h2p = h_hi + (2*2+prv)*BH_;

    // ---- A: gates0 = gp(W1H*h0_prv) + W1X*if(t) [XCD-local if]; cell -> h0_cur ----
    gemm_red_f<1, 8>(&w1x, if_own, w, lane, w, r16, ke, red);
    __syncthreads();
    cell_update(bias[0], cs[0], true, h0c, bid, bl, u2, red, gp);
    ++ep; gbar(bar, ep, tid, leader, xcc);

    // ---- B: gates1 = W2 * [h0_cur | h1_prv]; cell -> h1_cur ----
    if (w < 4) gemm_red_f<8, 32>(w2r, h0c, w*8,     lane, w, r16, ke, red);
    else       gemm_red_f<8, 32>(w2r, h1p, (w-4)*8, lane, w, r16, ke, red);
    __syncthreads();
    cell_update(bias[1], cs[1], false, h1c, bid, bl, u2, red, gp);
    ++ep; gbar(bar, ep, tid, leader, xcc);

    // ---- C: gates2 = W3 * [h1_cur | h2_prv]; cell -> h2_cur ----
    if (w < 4) gemm_red_f<8, 32>(w3r, h1c, w*8,     lane, w, r16, ke, red);
    else       gemm_red_f<8, 32>(w3r, h2p, (w-4)*8, lane, w, r16, ke, red);
    __syncthreads();
    cell_update(bias[2], cs[2], false, h2c, bid, bl, u2, red, gp);
    ++ep; gbar(bar, ep, tid, leader, xcc);

    // ---- D (no global barrier): gpart = W1H*h0_cur (all blocks);
    //      decoder replicated per-XCD (ranks 0..10) -> out(t), if(t+1) into if_own ----
    gemm_red_f<4, 32>(w1h, h0c, w*4, lane, w, r16, ke, red);
    __syncthreads();
#pragma unroll
    for (int q = 0; q < 4; ++q){
      float s = 0.f;
#pragma unroll
      for (int ww = 0; ww < 8; ++ww) s += red[ww][bl][q*4 + u2];
      gp[bl][q*4 + u2] = s;
    }
    if (rank < 11u){
      __syncthreads();                               // red reused by decoder
      f32x4 dacc[8];
#pragma unroll
      for (int bt = 0; bt < 8; ++bt) dacc[bt] = (f32x4){0,0,0,0};
#pragma unroll
      for (int kc = 0; kc < 4; ++kc){
#pragma unroll
        for (int bt = 0; bt < 8; ++bt){
          const int off = (bt*32 + w*4 + kc)*512 + lane*8;
          dacc[bt] = MFMA(ld8(h2c + off), wdr[kc], dacc[bt]);
        }
      }
#pragma unroll
      for (int bt = 0; bt < 8; ++bt)
#pragma unroll
        for (int e = 0; e < 4; ++e)
          red[w][bt*16 + ke*4 + e][r16] = dacc[bt][e];
      __syncthreads();
#pragma unroll
      for (int j = 0; j < 4; ++j){
        const int idx = tid + j*NT_;
        const int b = idx >> 4, fl = idx & 15;
        float v = bdec[rank*16 + fl];
#pragma unroll
        for (int ww = 0; ww < 8; ++ww) v += red[ww][b][fl];
        const int f = rank*16 + fl;
        if (f < F_){
          st4a(out + (size_t)b*TF_ + (size_t)t*F_ + f, v);   // 8 XCDs: identical values
          if (t + 1 < T_){
            const bool gt = (((t+1) % 10) < 5);
            const float in = gt ? x[(size_t)b*TF_ + (size_t)(t+1)*F_ + f] : v;
            const int idx2 = ((b >> 4)*8 + (f >> 5))*512 + ((f >> 3) & 3)*128
                           + (b & 15)*8 + (f & 7);
            if_own[idx2] = f2bf(in);                 // PLAIN store -> local L2 (private)
          }
        }
      }
    }
    ++ep2; lbar(bar, ep2, tid, xcc, n_my);
  }
}

// ---------- prep: permuted biases, decoder bias, initial in_frame (16 per-XCD copies) ----------
// permutation: permuted row i = blk*16 + g*4 + u2  <->  original j = (g<<10)|(blk<<2)|u2
__global__ void k_prep(const float* __restrict__ x,
                       const float* bi1, const float* bh1,
                       const float* bi2, const float* bh2,
                       const float* bi3, const float* bh3,
                       const float* bd_in,
                       float* __restrict__ bperm, float* __restrict__ bdec,
                       u16* __restrict__ if_base)
{
  const int i = blockIdx.x * blockDim.x + threadIdx.x;
  if (i < 3*G_){
    const int l = i >> 12, r = i & 4095;
    const int blk = r >> 4, g = (r >> 2) & 3, u2 = r & 3;
    const int j = (g << 10) | (blk << 2) | u2;
    const float* bi = (l == 0) ? bi1 : (l == 1) ? bi2 : bi3;
    const float* bh = (l == 0) ? bh1 : (l == 1) ? bh2 : bh3;
    bperm[i] = bi[j] + bh[j];
  }
  const int i2 = i - 3*G_;
  if (i2 >= 0 && i2 < 192) bdec[i2] = (i2 < F_) ? bd_in[i2] : 0.f;
  const int i3 = i2 - 192;
  if (i3 >= 0 && i3 < 16*B_*FX_){
    const int copy = i3 >> 15, rem = i3 & 32767;
    const int b = rem >> 8, f = rem & 255;
    const float v = (f < F_) ? x[(size_t)b*TF_ + f] : 0.f;   // t=0 is ground-truth
    const int idx = copy*32768 + ((b >> 4)*8 + (f >> 5))*512 + ((f >> 3) & 3)*128
                  + (b & 15)*8 + (f & 7);
    if_base[idx] = f2bf(v);
  }
}

// ---------- weight convert: fp32 -> bf16, permuted (blk*16 + g*4 + u2) ----------
__global__ void k_wcvt(const float* __restrict__ Wih1, const float* __restrict__ Whh1,
                       const float* __restrict__ Wih2, const float* __restrict__ Whh2,
                       const float* __restrict__ Wih3, const float* __restrict__ Whh3,
                       const float* __restrict__ Wd_in,
                       u16* __restrict__ W1X, u16* __restrict__ W1H,
                       u16* __restrict__ W2,  u16* __restrict__ W3,
                       u16* __restrict__ WD)
{
  const int region = blockIdx.y;
  const size_t stride = (size_t)gridDim.x * blockDim.x;
  const size_t i0 = (size_t)blockIdx.x * blockDim.x + threadIdx.x;
  if (region == 0){
    for (size_t i = i0; i < (size_t)G_*FX_; i += stride){
      const int r = (int)(i >> 8), k = (int)(i & 255);
      const int blk = r >> 4, g = (r >> 2) & 3, u2 = r & 3;
      const int j = (g << 10) | (blk << 2) | u2;
      W1X[i] = f2bf((k < F_) ? Wih1[(size_t)j*F_ + k] : 0.f);
    }
  } else if (region == 1){
    for (size_t i = i0; i < (size_t)G_*H_; i += stride){
      const int r = (int)(i >> 10), k = (int)(i & 1023);
      const int blk = r >> 4, g = (r >> 2) & 3, u2 = r & 3;
      const int j = (g << 10) | (blk << 2) | u2;
      W1H[i] = f2bf(Whh1[(size_t)j*H_ + k]);
    }
  } else if (region == 2){
    for (size_t i = i0; i < (size_t)G_*2048; i += stride){
      const int r = (int)(i >> 11), k = (int)(i & 2047);
      const int blk = r >> 4, g = (r >> 2) & 3, u2 = r & 3;
      const int j = (g << 10) | (blk << 2) | u2;
      W2[i] = f2bf((k < H_) ? Wih2[(size_t)j*H_ + k] : Whh2[(size_t)j*H_ + (k - H_)]);
    }
  } else if (region == 3){
    for (size_t i = i0; i < (size_t)G_*2048; i += stride){
      const int r = (int)(i >> 11), k = (int)(i & 2047);
      const int blk = r >> 4, g = (r >> 2) & 3, u2 = r & 3;
      const int j = (g << 10) | (blk << 2) | u2;
      W3[i] = f2bf((k < H_) ? Wih3[(size_t)j*H_ + k] : Whh3[(size_t)j*H_ + (k - H_)]);
    }
  } else {
    for (size_t i = i0; i < (size_t)176*H_; i += stride){
      const int r = (int)(i >> 10), k = (int)(i & 1023);
      WD[i] = f2bf((r < F_) ? Wd_in[(size_t)r*H_ + k] : 0.f);
    }
  }
}

extern "C" void kernel_launch(void* const* d_in, const int* in_sizes, int n_in,
                              void* d_out, int out_size, void* d_ws, size_t ws_size,
                              hipStream_t stream)
{
  const float* x    = (const float*)d_in[0];
  const float* Wih1 = (const float*)d_in[1];
  const float* bih1 = (const float*)d_in[2];
  const float* Whh1 = (const float*)d_in[3];
  const float* bhh1 = (const float*)d_in[4];
  const float* Wih2 = (const float*)d_in[5];
  const float* bih2 = (const float*)d_in[6];
  const float* Whh2 = (const float*)d_in[7];
  const float* bhh2 = (const float*)d_in[8];
  const float* Wih3 = (const float*)d_in[9];
  const float* bih3 = (const float*)d_in[10];
  const float* Whh3 = (const float*)d_in[11];
  const float* bhh3 = (const float*)d_in[12];
  const float* Wdec = (const float*)d_in[13];
  const float* bdec_in = (const float*)d_in[14];
  float* out = (float*)d_out;

  char* ws = (char*)d_ws;
  size_t off = 0;
  auto alloc = [&](size_t bytes) -> void* {
    void* p = ws + off;
    off = (off + bytes + 255) & ~(size_t)255;
    return p;
  };
  unsigned* bar = (unsigned*)alloc(4096);        // leaves/flags/census/local, 64B-spaced
  u16* h_hi    = (u16*)alloc((size_t)3*2*BH_*2);
  u16* if_base = (u16*)alloc((size_t)16*B_*FX_*2);   // 16 per-XCD private copies
  const size_t zero_bytes = off;                 // state zone: re-zeroed every launch
  u16* W1X = (u16*)alloc((size_t)G_*FX_*2);
  u16* W1H = (u16*)alloc((size_t)G_*H_*2);
  u16* W2  = (u16*)alloc((size_t)G_*2048*2);
  u16* W3  = (u16*)alloc((size_t)G_*2048*2);
  u16* WD  = (u16*)alloc((size_t)176*H_*2);
  float* bperm = (float*)alloc((size_t)3*G_*4);
  float* bdec  = (float*)alloc((size_t)192*4);

  hipMemsetAsync(d_ws, 0, zero_bytes, stream);
  k_prep<<<2097, 256, 0, stream>>>(x, bih1, bhh1, bih2, bhh2, bih3, bhh3, bdec_in,
                                   bperm, bdec, if_base);
  k_wcvt<<<dim3(2048, 5), 256, 0, stream>>>(Wih1, Whh1, Wih2, Whh2, Wih3, Whh3, Wdec,
                                            W1X, W1H, W2, W3, WD);
  k_main<<<NB_, NT_, 0, stream>>>(x, out, W1X, W1H, W2, W3, WD, bperm, bdec,
                                  h_hi, if_base, bar);
}

// Round 14
// 9799.716 us; speedup vs baseline: 1.3544x; 1.3544x over previous
//
#include <hip/hip_runtime.h>

typedef unsigned short u16;
typedef __attribute__((ext_vector_type(8))) short bf16x8;
typedef __attribute__((ext_vector_type(4))) float f32x4;
typedef __attribute__((ext_vector_type(4))) unsigned u32x4;

#define MFMA(a,b,c) __builtin_amdgcn_mfma_f32_16x16x32_bf16(a,b,c,0,0,0)

#define B_   128
#define T_   200
#define F_   171
#define FX_  256          // padded frame (8 K-chunks of 32; zero-padded weights)
#define H_   1024
#define G_   4096
#define TF_  (T_*F_)
#define BH_  (B_*H_)
#define BF_  (B_*FX_)     // 32768
#define NB_  256
#define NT_  512

__device__ __forceinline__ u16 f2bf(float v){
  union { float f; unsigned u; } c; c.f = v;
  unsigned r = (c.u + 0x7fffu + ((c.u >> 16) & 1u)) >> 16;   // RNE
  return (u16)r;
}
__device__ __forceinline__ float bf2f(u16 h){
  union { unsigned u; float f; } c; c.u = ((unsigned)h) << 16; return c.f;
}
__device__ __forceinline__ bf16x8 ld8(const u16* p){
  return *reinterpret_cast<const bf16x8*>(p);
}
// agent-scope write-through stores: visible at MALL, no release fence, no dirty L2 lines
__device__ __forceinline__ void st2a(u16* p, u16 v){
  __hip_atomic_store(p, v, __ATOMIC_RELAXED, __HIP_MEMORY_SCOPE_AGENT);
}
__device__ __forceinline__ void st4a(float* p, float v){
  __hip_atomic_store(p, v, __ATOMIC_RELAXED, __HIP_MEMORY_SCOPE_AGENT);
}
// cache-bypassing poll loads (sc0 sc1 -> served at MALL)
__device__ __forceinline__ u32x4 ld16_b(const unsigned* p){
  u32x4 v;
  asm volatile("global_load_dwordx4 %0, %1, off sc0 sc1\n\ts_waitcnt vmcnt(0)"
               : "=v"(v) : "v"(p) : "memory");
  return v;
}
__device__ __forceinline__ unsigned ld4_b(const unsigned* p){
  unsigned v;
  asm volatile("global_load_dword %0, %1, off sc0 sc1\n\ts_waitcnt vmcnt(0)"
               : "=v"(v) : "v"(p) : "memory");
  return v;
}
__device__ __forceinline__ float sigm(float v){ return 1.f / (1.f + __expf(-v)); }

// h/if/xfrag fragment-major layout: tile(bt,kcg) of 16 batch x 32 K = 1KB contiguous.
// bar dword layout: [0..255] gbar arrival slots (by bid) | [320+xcd*16] gbar flags |
//                   [576..591] census chk | [600] census iroot | [640+xcd*32+rank] lbar slots

// ---------- GLOBAL barrier: store-arrival, leader wave-polls 256 slots, 1 inv/XCD ----------
__device__ __forceinline__ void gbar(unsigned* bar, unsigned ep, int tid, int bid,
                                     bool leader, unsigned xcd){
  __syncthreads();                                   // drains vmcnt: st2a/st4a at MALL
  if (tid == 0)
    __hip_atomic_store(bar + bid, ep, __ATOMIC_RELAXED, __HIP_MEMORY_SCOPE_AGENT);
  if (leader){
    if (tid < 64){
      const unsigned* p = bar + tid*4;               // 64 lanes x 4 dwords = 256 slots
      for (;;){
        u32x4 v = ld16_b(p);
        const bool ok = (v[0] >= ep) && (v[1] >= ep) && (v[2] >= ep) && (v[3] >= ep);
        if (__all(ok)) break;
        __builtin_amdgcn_s_sleep(1);
      }
    }
    if (tid == 0){
      __builtin_amdgcn_fence(__ATOMIC_ACQUIRE, "agent");   // single buffer_inv, this XCD
      __hip_atomic_store(bar + 320 + xcd*16, ep, __ATOMIC_RELEASE, __HIP_MEMORY_SCOPE_AGENT);
    }
  } else {
    if (tid == 0){
      while (__hip_atomic_load(bar + 320 + xcd*16, __ATOMIC_RELAXED, __HIP_MEMORY_SCOPE_AGENT) < ep)
        __builtin_amdgcn_s_sleep(1);
    }
  }
  asm volatile("" ::: "memory");
  __syncthreads();
}

// ---------- LOCAL (per-XCD) barrier: leaderless, store-arrival + wave-parallel poll ----------
__device__ __forceinline__ void lbar(unsigned* bar, unsigned ep2, int tid,
                                     unsigned xcd, unsigned rank, unsigned n_my){
  __syncthreads();
  if (tid == 0)
    __hip_atomic_store(bar + 640 + xcd*32 + rank, ep2, __ATOMIC_RELAXED, __HIP_MEMORY_SCOPE_AGENT);
  if (tid < 64){
    const unsigned s = (unsigned)tid & 31u;
    const unsigned* p = bar + 640 + xcd*32 + s;
    for (;;){
      unsigned v = ld4_b(p);
      const bool ok = (s >= n_my) || (v >= ep2);
      if (__all(ok)) break;
      __builtin_amdgcn_s_sleep(1);
    }
  }
  asm volatile("" ::: "memory");
  __syncthreads();
}

// ---------- GEMM on resident weights, fragment-major A (single acc set) ----------
template<int KC, int TPR>
__device__ __forceinline__ void gemm_red_f(
    const bf16x8* wreg, const u16* __restrict__ hb,
    int kcg0, int lane, int w, int r16, int ke, float (*red)[128][20])
{
  f32x4 acc[8];
#pragma unroll
  for (int bt = 0; bt < 8; ++bt) acc[bt] = (f32x4){0,0,0,0};
#pragma unroll
  for (int kc = 0; kc < KC; ++kc){
#pragma unroll
    for (int bt = 0; bt < 8; ++bt){
      const int off = (bt*TPR + kcg0 + kc)*512 + lane*8;
      acc[bt] = MFMA(ld8(hb + off), wreg[kc], acc[bt]);
    }
  }
#pragma unroll
  for (int bt = 0; bt < 8; ++bt)
#pragma unroll
    for (int e = 0; e < 4; ++e)
      red[w][bt*16 + ke*4 + e][r16] = acc[bt][e];
}

// ---------- cell update: thread owns (batch bl, unit u2); block owns cols bid*16.. ----------
__device__ __forceinline__ void cell_update(
    const float* bias4, float& c, bool addgp,
    u16* __restrict__ ohh,
    int bid, int bl, int u2, float (*red)[128][20], float (*gp)[16])
{
  float g[4];
#pragma unroll
  for (int q = 0; q < 4; ++q){
    float s = bias4[q];
#pragma unroll
    for (int ww = 0; ww < 8; ++ww) s += red[ww][bl][q*4 + u2];
    if (addgp) s += gp[bl][q*4 + u2];
    g[q] = s;
  }
  const float cn = sigm(g[1])*c + sigm(g[0])*tanhf(g[2]);
  const float hn = sigm(g[3])*tanhf(cn);
  c = cn;
  const int col = bid*4 + u2;                        // frag-major store position
  const int idx = ((bl >> 4)*32 + (col >> 5))*512 + ((col >> 3) & 3)*128
                + (bl & 15)*8 + (col & 7);
  st2a(ohh + idx, f2bf(hn));
}

// ---------- main persistent kernel: 256 blocks x 512 thr; block = 16 gate-cols, ALL layers ----------
__global__ __attribute__((amdgpu_flat_work_group_size(NT_, NT_)))
           __attribute__((amdgpu_waves_per_eu(2, 2)))
void k_main(
    float* __restrict__ out,
    const u16* __restrict__ W1X, const u16* __restrict__ W1H,
    const u16* __restrict__ W2,  const u16* __restrict__ W3,
    const u16* __restrict__ WD,
    const float* __restrict__ bperm, const float* __restrict__ bdec,
    u16* __restrict__ h_hi, u16* __restrict__ if_base,
    const u16* __restrict__ xfrag,
    unsigned* __restrict__ bar)
{
  const int tid = threadIdx.x, bid = blockIdx.x;
  const int w = tid >> 6, lane = tid & 63, r16 = lane & 15, ke = lane >> 4;
  const int bl = tid >> 2, u2 = tid & 3;             // cell mapping: 128 b x 4 units
  __shared__ float red[8][128][20];                  // 80 KB K-reduce (padded rows)
  __shared__ float red2[4][128][20];                 // 40 KB gpart reduce (waves 0..3)
  __shared__ float gp[128][16];                      // 8 KB L1 h-part stash
  __shared__ unsigned s_info[3];

  // ---- one-time census: per-XCD rank, block count (proven R9) ----
  unsigned xcc; asm volatile("s_getreg_b32 %0, hwreg(HW_REG_XCC_ID)" : "=s"(xcc));
  xcc &= 15;
  if (tid == 0){
    unsigned* chk   = bar + 576;
    unsigned* iroot = bar + 600;
    const unsigned rank = __hip_atomic_fetch_add(&chk[xcc], 1u, __ATOMIC_RELAXED, __HIP_MEMORY_SCOPE_AGENT);
    __builtin_amdgcn_fence(__ATOMIC_RELEASE, "agent");
    __hip_atomic_fetch_add(iroot, 1u, __ATOMIC_RELAXED, __HIP_MEMORY_SCOPE_AGENT);
    while (__hip_atomic_load(iroot, __ATOMIC_RELAXED, __HIP_MEMORY_SCOPE_AGENT) < (unsigned)NB_)
      __builtin_amdgcn_s_sleep(1);
    __builtin_amdgcn_fence(__ATOMIC_ACQUIRE, "agent");
    s_info[0] = rank;
    s_info[1] = __hip_atomic_load(&chk[xcc], __ATOMIC_RELAXED, __HIP_MEMORY_SCOPE_AGENT);
  }
  __syncthreads();
  const unsigned rank = s_info[0];
  const bool leader = (rank == 0u);
  const unsigned n_my = s_info[1];
  u16* if_own = if_base + (size_t)xcc * BF_;         // per-XCD private if buffer

  // ---- resident weights: block's 16 gate-cols for all three layers ----
  const size_t wrow = (size_t)(bid*16 + r16);
  bf16x8 w2r[8], w3r[8], w1h8[8], w1x, wdr[4];
#pragma unroll
  for (int kc = 0; kc < 8; ++kc) w2r[kc] = ld8(W2 + wrow*2048 + w*256 + kc*32 + ke*8);
#pragma unroll
  for (int kc = 0; kc < 8; ++kc) w3r[kc] = ld8(W3 + wrow*2048 + w*256 + kc*32 + ke*8);
  if (w < 4){                                        // gpart fold: waves 0..3 hold W1H slice
#pragma unroll
    for (int kc = 0; kc < 8; ++kc)
      w1h8[kc] = ld8(W1H + wrow*1024 + (size_t)(w*8 + kc)*32 + ke*8);
  } else {
#pragma unroll
    for (int kc = 0; kc < 8; ++kc) w1h8[kc] = (bf16x8){0,0,0,0,0,0,0,0};
  }
  w1x = ld8(W1X + wrow*FX_ + w*32 + ke*8);

  // decoder: ranks 1..22 per XCD; (ct, part) = 11 col-tiles x 2 batch-halves
  const bool is_dec = (rank >= 1u) && (rank <= 22u);
  const int dr = is_dec ? (int)rank - 1 : 0;
  const int ct = dr % 11, part = dr / 11;
  const float bd = is_dec ? bdec[ct*16 + (tid & 15)] : 0.f;
  if (is_dec){
#pragma unroll
    for (int kc = 0; kc < 4; ++kc)
      wdr[kc] = ld8(WD + (size_t)(ct*16 + r16)*1024 + (w*4 + kc)*32 + ke*8);
  } else {
#pragma unroll
    for (int kc = 0; kc < 4; ++kc) wdr[kc] = (bf16x8){0,0,0,0,0,0,0,0};
  }

  float bias[3][4], cs[3] = {0.f, 0.f, 0.f};
#pragma unroll
  for (int l = 0; l < 3; ++l)
#pragma unroll
    for (int q = 0; q < 4; ++q) bias[l][q] = bperm[l*G_ + bid*16 + q*4 + u2];

  // zero the L1 h-part stash (t=0: h0_prev = 0)
  for (int i = tid; i < 128*16; i += NT_) gp[i >> 4][i & 15] = 0.f;
  __syncthreads();

  unsigned ep = 0, ep2 = 0;
  for (int t = 0; t < T_; ++t){
    const int cur = t & 1, prv = cur ^ 1;
    const bool need_if = (t + 1 < T_) && (((t + 1) % 10) >= 5);
    u16* h0c = h_hi + (0*2+cur)*BH_;
    u16* h1c = h_hi + (1*2+cur)*BH_;
    u16* h2c = h_hi + (2*2+cur)*BH_;
    const u16* h1p = h_hi + (1*2+prv)*BH_;
    const u16* h2p = h_hi + (2*2+prv)*BH_;

    // ---- A: gates0 = gp(W1H*h0_prv) + W1X*if(t); cell -> h0_cur ----
    {
      const u16* asrc = ((t % 10) < 5) ? (xfrag + (size_t)t * BF_) : if_own;
      gemm_red_f<1, 8>(&w1x, asrc, w, lane, w, r16, ke, red);
    }
    __syncthreads();
    cell_update(bias[0], cs[0], true, h0c, bid, bl, u2, red, gp);
    ++ep; gbar(bar, ep, tid, bid, leader, xcc);

    // ---- B: gates1 = W2 * [h0_cur | h1_prv]; cell -> h1_cur.
    //      FOLD: waves 0..3 also accumulate gpart = W1H * h0_cur (for A of t+1) ----
    if (w < 4){
#pragma unroll
      for (int bt = 0; bt < 8; ++bt){
        f32x4 a = {0,0,0,0}, g = {0,0,0,0};
#pragma unroll
        for (int kc = 0; kc < 8; ++kc){
          const bf16x8 pa = ld8(h0c + (bt*32 + w*8 + kc)*512 + lane*8);
          a = MFMA(pa, w2r[kc], a);
          g = MFMA(pa, w1h8[kc], g);
        }
#pragma unroll
        for (int e = 0; e < 4; ++e){
          red [w][bt*16 + ke*4 + e][r16] = a[e];
          red2[w][bt*16 + ke*4 + e][r16] = g[e];
        }
      }
    } else {
      gemm_red_f<8, 32>(w2r, h1p, (w-4)*8, lane, w, r16, ke, red);
    }
    __syncthreads();
    cell_update(bias[1], cs[1], false, h1c, bid, bl, u2, red, gp);
#pragma unroll
    for (int q = 0; q < 4; ++q){                     // gp refresh for next step's A
      gp[bl][q*4 + u2] = red2[0][bl][q*4 + u2] + red2[1][bl][q*4 + u2]
                       + red2[2][bl][q*4 + u2] + red2[3][bl][q*4 + u2];
    }
    ++ep; gbar(bar, ep, tid, bid, leader, xcc);

    // ---- C: gates2 = W3 * [h1_cur | h2_prv]; cell -> h2_cur ----
    if (w < 4) gemm_red_f<8, 32>(w3r, h1c, w*8,     lane, w, r16, ke, red);
    else       gemm_red_f<8, 32>(w3r, h2p, (w-4)*8, lane, w, r16, ke, red);
    __syncthreads();
    cell_update(bias[2], cs[2], false, h2c, bid, bl, u2, red, gp);
    ++ep; gbar(bar, ep, tid, bid, leader, xcc);

    // ---- D: decoder (ranks 1..22 per XCD) -> out(t); if(t+1) only when AR-next ----
    if (is_dec){
      f32x4 dacc[4];
#pragma unroll
      for (int bt = 0; bt < 4; ++bt) dacc[bt] = (f32x4){0,0,0,0};
#pragma unroll
      for (int kc = 0; kc < 4; ++kc){
#pragma unroll
        for (int bt = 0; bt < 4; ++bt){
          const int off = ((part*4 + bt)*32 + w*4 + kc)*512 + lane*8;
          dacc[bt] = MFMA(ld8(h2c + off), wdr[kc], dacc[bt]);
        }
      }
#pragma unroll
      for (int bt = 0; bt < 4; ++bt)
#pragma unroll
        for (int e = 0; e < 4; ++e)
          red[w][bt*16 + ke*4 + e][r16] = dacc[bt][e];
      __syncthreads();
      {
        const int fl = tid & 15;
#pragma unroll
        for (int j = 0; j < 2; ++j){
          const int b_loc = (tid >> 4) + j*32;       // 0..63
          float v = bd;
#pragma unroll
          for (int ww = 0; ww < 8; ++ww) v += red[ww][b_loc][fl];
          const int f = ct*16 + fl, b = part*64 + b_loc;
          if (f < F_){
            st4a(out + (size_t)b*TF_ + (size_t)t*F_ + f, v);   // 8 XCDs: identical values
            if (need_if){
              const int idx2 = ((b >> 4)*8 + (f >> 5))*512 + ((f >> 3) & 3)*128
                             + (b & 15)*8 + (f & 7);
              if_own[idx2] = f2bf(v);                // PLAIN store -> local L2 (private)
            }
          }
        }
      }
      __syncthreads();                               // red free before A(t+1) rewrites it
    }
    if (need_if){ ++ep2; lbar(bar, ep2, tid, xcc, rank, n_my); }
  }
}

// ---------- prep: permuted biases, decoder bias, frag-major x frames ----------
// permutation: permuted row i = blk*16 + g*4 + u2  <->  original j = (g<<10)|(blk<<2)|u2
__global__ void k_prep(const float* __restrict__ x,
                       const float* bi1, const float* bh1,
                       const float* bi2, const float* bh2,
                       const float* bi3, const float* bh3,
                       const float* bd_in,
                       float* __restrict__ bperm, float* __restrict__ bdec,
                       u16* __restrict__ xfrag)
{
  const int i = blockIdx.x * blockDim.x + threadIdx.x;
  if (i < 3*G_){
    const int l = i >> 12, r = i & 4095;
    const int blk = r >> 4, g = (r >> 2) & 3, u2 = r & 3;
    const int j = (g << 10) | (blk << 2) | u2;
    const float* bi = (l == 0) ? bi1 : (l == 1) ? bi2 : bi3;
    const float* bh = (l == 0) ? bh1 : (l == 1) ? bh2 : bh3;
    bperm[i] = bi[j] + bh[j];
  }
  const int i2 = i - 3*G_;
  if (i2 >= 0 && i2 < 192) bdec[i2] = (i2 < F_) ? bd_in[i2] : 0.f;
  const int i3 = i2 - 192;
  if (i3 >= 0 && i3 < T_*BF_){
    const int t = i3 >> 15, rem = i3 & (BF_ - 1);
    const int b = rem >> 8, f = rem & 255;
    const float v = (f < F_) ? x[(size_t)b*TF_ + (size_t)t*F_ + f] : 0.f;
    const int idx = ((b >> 4)*8 + (f >> 5))*512 + ((f >> 3) & 3)*128 + (b & 15)*8 + (f & 7);
    xfrag[(size_t)t*BF_ + idx] = f2bf(v);
  }
}

// ---------- weight convert: fp32 -> bf16, permuted (blk*16 + g*4 + u2) ----------
__global__ void k_wcvt(const float* __restrict__ Wih1, const float* __restrict__ Whh1,
                       const float* __restrict__ Wih2, const float* __restrict__ Whh2,
                       const float* __restrict__ Wih3, const float* __restrict__ Whh3,
                       const float* __restrict__ Wd_in,
                       u16* __restrict__ W1X, u16* __restrict__ W1H,
                       u16* __restrict__ W2,  u16* __restrict__ W3,
                       u16* __restrict__ WD)
{
  const int region = blockIdx.y;
  const size_t stride = (size_t)gridDim.x * blockDim.x;
  const size_t i0 = (size_t)blockIdx.x * blockDim.x + threadIdx.x;
  if (region == 0){
    for (size_t i = i0; i < (size_t)G_*FX_; i += stride){
      const int r = (int)(i >> 8), k = (int)(i & 255);
      const int blk = r >> 4, g = (r >> 2) & 3, u2 = r & 3;
      const int j = (g << 10) | (blk << 2) | u2;
      W1X[i] = f2bf((k < F_) ? Wih1[(size_t)j*F_ + k] : 0.f);
    }
  } else if (region == 1){
    for (size_t i = i0; i < (size_t)G_*H_; i += stride){
      const int r = (int)(i >> 10), k = (int)(i & 1023);
      const int blk = r >> 4, g = (r >> 2) & 3, u2 = r & 3;
      const int j = (g << 10) | (blk << 2) | u2;
      W1H[i] = f2bf(Whh1[(size_t)j*H_ + k]);
    }
  } else if (region == 2){
    for (size_t i = i0; i < (size_t)G_*2048; i += stride){
      const int r = (int)(i >> 11), k = (int)(i & 2047);
      const int blk = r >> 4, g = (r >> 2) & 3, u2 = r & 3;
      const int j = (g << 10) | (blk << 2) | u2;
      W2[i] = f2bf((k < H_) ? Wih2[(size_t)j*H_ + k] : Whh2[(size_t)j*H_ + (k - H_)]);
    }
  } else if (region == 3){
    for (size_t i = i0; i < (size_t)G_*2048; i += stride){
      const int r = (int)(i >> 11), k = (int)(i & 2047);
      const int blk = r >> 4, g = (r >> 2) & 3, u2 = r & 3;
      const int j = (g << 10) | (blk << 2) | u2;
      W3[i] = f2bf((k < H_) ? Wih3[(size_t)j*H_ + k] : Whh3[(size_t)j*H_ + (k - H_)]);
    }
  } else {
    for (size_t i = i0; i < (size_t)176*H_; i += stride){
      const int r = (int)(i >> 10), k = (int)(i & 1023);
      WD[i] = f2bf((r < F_) ? Wd_in[(size_t)r*H_ + k] : 0.f);
    }
  }
}

extern "C" void kernel_launch(void* const* d_in, const int* in_sizes, int n_in,
                              void* d_out, int out_size, void* d_ws, size_t ws_size,
                              hipStream_t stream)
{
  const float* x    = (const float*)d_in[0];
  const float* Wih1 = (const float*)d_in[1];
  const float* bih1 = (const float*)d_in[2];
  const float* Whh1 = (const float*)d_in[3];
  const float* bhh1 = (const float*)d_in[4];
  const float* Wih2 = (const float*)d_in[5];
  const float* bih2 = (const float*)d_in[6];
  const float* Whh2 = (const float*)d_in[7];
  const float* bhh2 = (const float*)d_in[8];
  const float* Wih3 = (const float*)d_in[9];
  const float* bih3 = (const float*)d_in[10];
  const float* Whh3 = (const float*)d_in[11];
  const float* bhh3 = (const float*)d_in[12];
  const float* Wdec = (const float*)d_in[13];
  const float* bdec_in = (const float*)d_in[14];
  float* out = (float*)d_out;

  char* ws = (char*)d_ws;
  size_t off = 0;
  auto alloc = [&](size_t bytes) -> void* {
    void* p = ws + off;
    off = (off + bytes + 255) & ~(size_t)255;
    return p;
  };
  unsigned* bar = (unsigned*)alloc(8192);        // arrivals/flags/census/lbar slots
  u16* h_hi    = (u16*)alloc((size_t)3*2*BH_*2);
  u16* if_base = (u16*)alloc((size_t)16*BF_*2);      // 16 per-XCD private copies
  const size_t zero_bytes = off;                 // state zone: re-zeroed every launch
  u16* xfrag = (u16*)alloc((size_t)T_*BF_*2);        // frag-major x frames (all t)
  u16* W1X = (u16*)alloc((size_t)G_*FX_*2);
  u16* W1H = (u16*)alloc((size_t)G_*H_*2);
  u16* W2  = (u16*)alloc((size_t)G_*2048*2);
  u16* W3  = (u16*)alloc((size_t)G_*2048*2);
  u16* WD  = (u16*)alloc((size_t)176*H_*2);
  float* bperm = (float*)alloc((size_t)3*G_*4);
  float* bdec  = (float*)alloc((size_t)192*4);

  hipMemsetAsync(d_ws, 0, zero_bytes, stream);
  k_prep<<<25651, 256, 0, stream>>>(x, bih1, bhh1, bih2, bhh2, bih3, bhh3, bdec_in,
                                    bperm, bdec, xfrag);
  k_wcvt<<<dim3(2048, 5), 256, 0, stream>>>(Wih1, Whh1, Wih2, Whh2, Wih3, Whh3, Wdec,
                                            W1X, W1H, W2, W3, WD);
  k_main<<<NB_, NT_, 0, stream>>>(out, W1X, W1H, W2, W3, WD, bperm, bdec,
                                  h_hi, if_base, xfrag, bar);
}